// Round 1
// baseline (7021.538 us; speedup 1.0000x reference)
//
#include <hip/hip_runtime.h>

// ---------------------------------------------------------------------------
// AdaptiveSoftmaxRNN: emb -> 2-layer LSTM -> adaptive log-softmax (head + 2 tails)
// Strategy: bf16 MFMA for all GEMM-shaped work, fused online-LSE epilogue for
// the classifier (never materialize logits), fp32 LSTM cell math.
// ---------------------------------------------------------------------------

typedef float f32x4 __attribute__((ext_vector_type(4)));
typedef short s16x8 __attribute__((ext_vector_type(8)));

#define MFMA_B16(A_,B_,C_) __builtin_amdgcn_mfma_f32_16x16x32_bf16((A_),(B_),(C_),0,0,0)

static __device__ __forceinline__ ushort f2b(float f){
  uint u = __float_as_uint(f);
  u += 0x7fffu + ((u>>16)&1u);          // RNE
  return (ushort)(u>>16);
}
static __device__ __forceinline__ float b2f(ushort b){ return __uint_as_float(((uint)b)<<16); }

static __device__ __forceinline__ float dot8(int4 a, int4 b){
  const ushort* pa=(const ushort*)&a; const ushort* pb=(const ushort*)&b;
  float s=0.f;
  #pragma unroll
  for(int i=0;i<8;i++) s += b2f(pa[i])*b2f(pb[i]);
  return s;
}

// -------------------- fp32 -> bf16 convert (zero-pads tail) ------------------
__global__ void cvt_k(const float* __restrict__ in, ushort* __restrict__ out,
                      long n, long npad){
  long i = ((long)blockIdx.x*blockDim.x + threadIdx.x)*4;
  if(i>=npad) return;
  uint2 st;
  if(i<n){
    float4 v=*(const float4*)(in+i);
    st.x = ((uint)f2b(v.y)<<16)|f2b(v.x);
    st.y = ((uint)f2b(v.w)<<16)|f2b(v.z);
  } else { st.x=0u; st.y=0u; }
  *(uint2*)(out+i) = st;
}

__global__ void bias_k(const float* __restrict__ a, const float* __restrict__ b,
                       float* __restrict__ o){
  int i = blockIdx.x*256+threadIdx.x;
  o[i]=a[i]+b[i];
}

// -------------------- embedding gather -> bf16 -------------------------------
// grid 4096 blocks, 128 threads; one block per token row.
__global__ void emb_gather(const float* __restrict__ emb, const int* __restrict__ tokens,
                           ushort* __restrict__ out){
  const int n = blockIdx.x;
  const long tok = tokens[n];
  const float4* src = (const float4*)(emb + tok*1024);
  float4 x = src[threadIdx.x*2], y = src[threadIdx.x*2+1];
  uint p0 = ((uint)f2b(x.y)<<16)|f2b(x.x);
  uint p1 = ((uint)f2b(x.w)<<16)|f2b(x.z);
  uint p2 = ((uint)f2b(y.y)<<16)|f2b(y.x);
  uint p3 = ((uint)f2b(y.w)<<16)|f2b(y.z);
  int4 v = make_int4((int)p0,(int)p1,(int)p2,(int)p3);
  *(int4*)(out + (long)n*1024 + threadIdx.x*8) = v;
}

// -------------------- bf16 MFMA GEMM: C[M,N] = A[M,K] * B[N,K]^T --------------
// 128x128 tile, BK=64, 4 waves (each 32 rows x 128 cols), XOR-swizzled LDS,
// register-prefetch double buffer. OM: 1 = f32 out + bias, 2 = bf16 out.
template<int OM>
__global__ __launch_bounds__(256,2) void gemm_bt(const ushort* __restrict__ A,
    const ushort* __restrict__ B, float* __restrict__ Cf, ushort* __restrict__ Cb,
    const float* __restrict__ bias, int K, int ldc)
{
  __shared__ ushort As[128*64];
  __shared__ ushort Bs[128*64];
  const int tid = threadIdx.x;
  const int w = tid>>6, l = tid&63, ln = l&15, hi = l>>4;
  const long r0 = (long)blockIdx.x*128, c0 = (long)blockIdx.y*128;
  const int nkt = K>>6;
  int4 ra[4], rb[4];

  auto g_load = [&](int kt){
    #pragma unroll
    for(int i=0;i<4;i++){
      int c = i*256+tid; int row=c>>3, kg=c&7;
      ra[i] = *(const int4*)(A + (r0+row)*(long)K + kt*64 + kg*8);
      rb[i] = *(const int4*)(B + (c0+row)*(long)K + kt*64 + kg*8);
    }
  };
  auto s_store = [&](){
    #pragma unroll
    for(int i=0;i<4;i++){
      int c=i*256+tid; int row=c>>3, kg=c&7;
      int sl = (kg ^ (row&7))*8;
      *(int4*)&As[row*64 + sl] = ra[i];
      *(int4*)&Bs[row*64 + sl] = rb[i];
    }
  };

  f32x4 acc[2][8] = {};
  g_load(0);
  for(int kt=0; kt<nkt; ++kt){
    __syncthreads();
    s_store();
    __syncthreads();
    if (kt+1 < nkt) g_load(kt+1);
    #pragma unroll
    for(int kk=0;kk<2;kk++){
      int rowa0 = w*32 + ln;
      s16x8 a0 = *(const s16x8*)&As[rowa0*64 + (((kk*4+hi) ^ (rowa0&7))*8)];
      int rowa1 = rowa0 + 16;
      s16x8 a1 = *(const s16x8*)&As[rowa1*64 + (((kk*4+hi) ^ (rowa1&7))*8)];
      s16x8 bb[8];
      #pragma unroll
      for(int ni=0;ni<8;ni++){
        int rowb = ni*16 + ln;
        bb[ni] = *(const s16x8*)&Bs[rowb*64 + (((kk*4+hi) ^ (rowb&7))*8)];
      }
      #pragma unroll
      for(int ni=0;ni<8;ni++){
        acc[0][ni] = MFMA_B16(a0, bb[ni], acc[0][ni]);
        acc[1][ni] = MFMA_B16(a1, bb[ni], acc[1][ni]);
      }
    }
  }
  #pragma unroll
  for(int mi=0;mi<2;mi++){
    #pragma unroll
    for(int ni=0;ni<8;ni++){
      long gr = r0 + w*32 + mi*16 + hi*4;
      long gc = c0 + ni*16 + ln;
      f32x4 v = acc[mi][ni];
      #pragma unroll
      for(int r=0;r<4;r++){
        if (OM==2)      Cb[(gr+r)*ldc + gc] = f2b(v[r]);
        else            Cf[(gr+r)*ldc + gc] = v[r] + bias[gc];
      }
    }
  }
}

// -------------------- fused GEMM + online logsumexp partials ------------------
// A[M=4096,K] * B[C,K]^T ; per-row (max, sumexp) over this block's class tiles.
// grid (32 rowblocks, nsplit). part layout: [row][split][2].
__global__ __launch_bounds__(256,2) void lse_gemm(const ushort* __restrict__ A,
    const ushort* __restrict__ B, int K, int creal, int nct, int nsplit,
    float* __restrict__ part)
{
  __shared__ ushort As[128*64];
  __shared__ ushort Bs[128*64];
  const int tid=threadIdx.x, w=tid>>6, l=tid&63, ln=l&15, hi=l>>4;
  const long r0 = (long)blockIdx.x*128;
  const int split = blockIdx.y;
  const int nkt = K>>6;

  float M_[2][4], S_[2][4];
  #pragma unroll
  for(int mi=0;mi<2;mi++)
    #pragma unroll
    for(int r=0;r<4;r++){ M_[mi][r]=-1e30f; S_[mi][r]=0.f; }

  for(int ct=split; ct<nct; ct+=nsplit){
    const ushort* Bt = B + (long)ct*128*K;
    int4 ra[4], rb[4];
    auto g_load = [&](int kt){
      #pragma unroll
      for(int i=0;i<4;i++){
        int c = i*256+tid; int row=c>>3, kg=c&7;
        ra[i] = *(const int4*)(A  + (r0+row)*(long)K + kt*64 + kg*8);
        rb[i] = *(const int4*)(Bt + (long)row*K      + kt*64 + kg*8);
      }
    };
    auto s_store = [&](){
      #pragma unroll
      for(int i=0;i<4;i++){
        int c=i*256+tid; int row=c>>3, kg=c&7;
        int sl = (kg ^ (row&7))*8;
        *(int4*)&As[row*64 + sl] = ra[i];
        *(int4*)&Bs[row*64 + sl] = rb[i];
      }
    };

    f32x4 acc[2][8] = {};
    g_load(0);
    for(int kt=0; kt<nkt; ++kt){
      __syncthreads();
      s_store();
      __syncthreads();
      if (kt+1 < nkt) g_load(kt+1);
      #pragma unroll
      for(int kk=0;kk<2;kk++){
        int rowa0 = w*32 + ln;
        s16x8 a0 = *(const s16x8*)&As[rowa0*64 + (((kk*4+hi) ^ (rowa0&7))*8)];
        int rowa1 = rowa0 + 16;
        s16x8 a1 = *(const s16x8*)&As[rowa1*64 + (((kk*4+hi) ^ (rowa1&7))*8)];
        s16x8 bb[8];
        #pragma unroll
        for(int ni=0;ni<8;ni++){
          int rowb = ni*16 + ln;
          bb[ni] = *(const s16x8*)&Bs[rowb*64 + (((kk*4+hi) ^ (rowb&7))*8)];
        }
        #pragma unroll
        for(int ni=0;ni<8;ni++){
          acc[0][ni] = MFMA_B16(a0, bb[ni], acc[0][ni]);
          acc[1][ni] = MFMA_B16(a1, bb[ni], acc[1][ni]);
        }
      }
    }
    // online-LSE epilogue for this 128-class tile
    int cbase = ct*128;
    #pragma unroll
    for(int mi=0;mi<2;mi++){
      #pragma unroll
      for(int r=0;r<4;r++){
        float vm=-1e30f;
        #pragma unroll
        for(int ni=0;ni<8;ni++){
          int gc=cbase+ni*16+ln;
          float x=acc[mi][ni][r];
          if(gc<creal) vm=fmaxf(vm,x);
        }
        vm=fmaxf(vm,__shfl_xor(vm,1)); vm=fmaxf(vm,__shfl_xor(vm,2));
        vm=fmaxf(vm,__shfl_xor(vm,4)); vm=fmaxf(vm,__shfl_xor(vm,8));
        float vs=0.f;
        #pragma unroll
        for(int ni=0;ni<8;ni++){
          int gc=cbase+ni*16+ln;
          if(gc<creal) vs+=__expf(acc[mi][ni][r]-vm);
        }
        vs+=__shfl_xor(vs,1); vs+=__shfl_xor(vs,2);
        vs+=__shfl_xor(vs,4); vs+=__shfl_xor(vs,8);
        float Mo=M_[mi][r];
        float Mn=fmaxf(Mo,vm);
        S_[mi][r]=S_[mi][r]*__expf(Mo-Mn)+vs*__expf(vm-Mn);
        M_[mi][r]=Mn;
      }
    }
  }
  if(ln==0){
    #pragma unroll
    for(int mi=0;mi<2;mi++){
      #pragma unroll
      for(int r=0;r<4;r++){
        long grow = r0 + w*32 + mi*16 + hi*4 + r;
        part[(grow*nsplit + split)*2 + 0] = M_[mi][r];
        part[(grow*nsplit + split)*2 + 1] = S_[mi][r];
      }
    }
  }
}

// -------------------- one LSTM step (MFMA recurrent GEMM + cell) --------------
// grid 64 blocks x 256 threads; block bj handles 16 hidden cols (all 4 gates).
// 4 waves split K=1024 into quarters; LDS reduce; wave 0 applies fp32 cell.
__global__ __launch_bounds__(256,1) void lstm_step(const ushort* __restrict__ hprev,
    const ushort* __restrict__ whh, const float* __restrict__ pgrow,
    float* __restrict__ cst, ushort* __restrict__ hout)
{
  __shared__ ushort a_lds[32*1032];         // +8 ushort pad per row: bank spread
  __shared__ float red[3*2*4*64*4];
  const int tid=threadIdx.x, w=tid>>6, l=tid&63, ln=l&15, hi=l>>4;
  const int j0 = blockIdx.x*16;

  #pragma unroll
  for(int i=0;i<16;i++){
    int c=i*256+tid; int row=c>>7, kg=c&127;
    int4 v = *(const int4*)(hprev + row*1024 + kg*8);
    *(int4*)&a_lds[row*1032 + kg*8] = v;
  }
  __syncthreads();

  f32x4 acc[2][4]={};
  const int kw = w*256;
  #pragma unroll
  for(int s=0;s<8;s++){
    int kb = kw + s*32;
    s16x8 a0 = *(const s16x8*)&a_lds[ln*1032 + kb + hi*8];
    s16x8 a1 = *(const s16x8*)&a_lds[(16+ln)*1032 + kb + hi*8];
    #pragma unroll
    for(int g=0;g<4;g++){
      s16x8 bv = *(const s16x8*)(whh + (long)(g*1024 + j0 + ln)*1024 + kb + hi*8);
      acc[0][g] = MFMA_B16(a0, bv, acc[0][g]);
      acc[1][g] = MFMA_B16(a1, bv, acc[1][g]);
    }
  }
  __syncthreads();
  if(w>0){
    #pragma unroll
    for(int mi=0;mi<2;mi++)
      #pragma unroll
      for(int g=0;g<4;g++)
        *(f32x4*)&red[((((w-1)*2+mi)*4+g)*64 + l)*4] = acc[mi][g];
  }
  __syncthreads();
  if(w==0){
    #pragma unroll
    for(int mi=0;mi<2;mi++){
      f32x4 sv[4];
      #pragma unroll
      for(int g=0;g<4;g++){
        f32x4 s = acc[mi][g];
        #pragma unroll
        for(int ww=0;ww<3;ww++) s += *(const f32x4*)&red[(((ww*2+mi)*4+g)*64 + l)*4];
        sv[g]=s;
      }
      const int j = j0 + ln;
      #pragma unroll
      for(int r=0;r<4;r++){
        int b = mi*16 + hi*4 + r;
        const float* pg = pgrow + (long)b*4096;
        float xi = sv[0][r] + pg[j];
        float xf = sv[1][r] + pg[1024+j];
        float xg = sv[2][r] + pg[2048+j];
        float xo = sv[3][r] + pg[3072+j];
        float co = cst[b*1024+j];
        float si = 1.f/(1.f+__expf(-xi));
        float sf = 1.f/(1.f+__expf(-xf));
        float so = 1.f/(1.f+__expf(-xo));
        float cn = sf*co + si*tanhf(xg);
        float h  = so*tanhf(cn);
        cst[b*1024+j] = cn;
        hout[b*1024+j] = f2b(h);
      }
    }
  }
}

// -------------------- combine partials + target logits + output ---------------
// 1024 blocks x 256 threads; one wave per token row.
__global__ __launch_bounds__(256) void combine_k(const int* __restrict__ targets,
  const ushort* __restrict__ flat, const ushort* __restrict__ headw,
  const ushort* __restrict__ th0, const ushort* __restrict__ t0w2,
  const ushort* __restrict__ th1, const ushort* __restrict__ t1w2,
  const float* __restrict__ ph, const float* __restrict__ p0, const float* __restrict__ p1,
  float* __restrict__ out)
{
  const int w = threadIdx.x>>6, l = threadIdx.x&63;
  const int n = blockIdx.x*4 + w;
  const int t = targets[n];
  const int cl = (t>=20000)+(t>=50000);
  const int gi = (cl==0)? t : (20000+cl-1);

  // head logsumexp from 16 split partials
  float Mp=-1e30f, Sp=0.f;
  if(l<16){ Mp=ph[((long)n*16+l)*2]; Sp=ph[((long)n*16+l)*2+1]; }
  #pragma unroll
  for(int s=1;s<64;s<<=1){
    float Mo=__shfl_xor(Mp,s), So=__shfl_xor(Sp,s);
    float Mn=fmaxf(Mp,Mo);
    Sp=Sp*__expf(Mp-Mn)+So*__expf(Mo-Mn); Mp=Mn;
  }
  float lseh = Mp + __logf(Sp);

  // head target logit: dot(flat[n], headW[gi]) over K=1024
  const ushort* fr = flat + (long)n*1024;
  const ushort* wr = headw + (long)gi*1024;
  float acc = 0.f;
  #pragma unroll
  for(int i=0;i<2;i++){
    int4 a=*(const int4*)(fr + l*16 + i*8);
    int4 b=*(const int4*)(wr + l*16 + i*8);
    acc += dot8(a,b);
  }
  #pragma unroll
  for(int s=1;s<64;s<<=1) acc += __shfl_xor(acc,s);
  float res = acc - lseh;

  if(cl>0){
    const float* pp = (cl==1)? p0 : p1;
    float Mt=-1e30f, St=0.f;
    if(l<16){ Mt=pp[((long)n*16+l)*2]; St=pp[((long)n*16+l)*2+1]; }
    #pragma unroll
    for(int s=1;s<64;s<<=1){
      float Mo=__shfl_xor(Mt,s), So=__shfl_xor(St,s);
      float Mn=fmaxf(Mt,Mo);
      St=St*__expf(Mt-Mn)+So*__expf(Mo-Mn); Mt=Mn;
    }
    float lset = Mt + __logf(St);
    int Kt  = (cl==1)?512:256;
    int lo  = (cl==1)?20000:50000;
    int osz = (cl==1)?30000:50000;
    int rel = t-lo; rel = rel<0?0:rel; rel = rel>osz-1?osz-1:rel;
    const ushort* thr = ((cl==1)? th0 : th1) + (long)n*Kt;
    const ushort* w2r = ((cl==1)? t0w2 : t1w2) + (long)rel*Kt;
    float a2=0.f;
    if(Kt==512){
      int4 a=*(const int4*)(thr + l*8); int4 b=*(const int4*)(w2r + l*8);
      a2 = dot8(a,b);
    } else {
      int2 a=*(const int2*)(thr + l*4); int2 b=*(const int2*)(w2r + l*4);
      const ushort* pa=(const ushort*)&a; const ushort* pb=(const ushort*)&b;
      #pragma unroll
      for(int i=0;i<4;i++) a2 += b2f(pa[i])*b2f(pb[i]);
    }
    #pragma unroll
    for(int s=1;s<64;s<<=1) a2 += __shfl_xor(a2,s);
    res += a2 - lset;
  }
  if(l==0) out[n] = res;
}

__global__ void loss_k(const float* __restrict__ out, float* __restrict__ loss){
  __shared__ float sm[4];
  int tid=threadIdx.x;
  float s=0.f;
  for(int i=tid;i<4096;i+=256) s+=out[i];
  #pragma unroll
  for(int k=1;k<64;k<<=1) s+=__shfl_xor(s,k);
  if((tid&63)==0) sm[tid>>6]=s;
  __syncthreads();
  if(tid==0) loss[0] = -(sm[0]+sm[1]+sm[2]+sm[3])*(1.f/4096.f);
}

// ---------------------------------------------------------------------------
extern "C" void kernel_launch(void* const* d_in, const int* in_sizes, int n_in,
                              void* d_out, int out_size, void* d_ws, size_t ws_size,
                              hipStream_t stream)
{
  const int*   tokens = (const int*)d_in[0];
  const int*   targets= (const int*)d_in[1];
  const float* embW   = (const float*)d_in[2];
  const float* wih0 = (const float*)d_in[3];
  const float* whh0 = (const float*)d_in[4];
  const float* bih0 = (const float*)d_in[5];
  const float* bhh0 = (const float*)d_in[6];
  const float* wih1 = (const float*)d_in[7];
  const float* whh1 = (const float*)d_in[8];
  const float* bih1 = (const float*)d_in[9];
  const float* bhh1 = (const float*)d_in[10];
  const float* h0   = (const float*)d_in[11];
  const float* c0   = (const float*)d_in[12];
  const float* headW= (const float*)d_in[13];
  const float* t0w1 = (const float*)d_in[14];
  const float* t0w2 = (const float*)d_in[15];
  const float* t1w1 = (const float*)d_in[16];
  const float* t1w2 = (const float*)d_in[17];
  float* out = (float*)d_out;

  char* ws = (char*)d_ws;
  size_t off=0;
  auto alloc=[&](size_t b){ size_t o=off; off=(off+b+255)&~(size_t)255; return o; };
  ushort* XEMB  = (ushort*)(ws+alloc(4096UL*1024*2));
  ushort* WIH0B = (ushort*)(ws+alloc(4096UL*1024*2));
  ushort* WHH0B = (ushort*)(ws+alloc(4096UL*1024*2));
  ushort* WIH1B = (ushort*)(ws+alloc(4096UL*1024*2));
  ushort* WHH1B = (ushort*)(ws+alloc(4096UL*1024*2));
  ushort* HEADWB= (ushort*)(ws+alloc(20096UL*1024*2));
  ushort* T0W1B = (ushort*)(ws+alloc(512UL*1024*2));
  ushort* T0W2B = (ushort*)(ws+alloc(30080UL*512*2));
  ushort* T1W1B = (ushort*)(ws+alloc(256UL*1024*2));
  ushort* T1W2B = (ushort*)(ws+alloc(50048UL*256*2));
  float*  PG    = (float*)(ws+alloc(4096UL*4096*4));
  ushort* HB0   = (ushort*)(ws+alloc(129UL*32*1024*2));
  ushort* HB1   = (ushort*)(ws+alloc(129UL*32*1024*2));
  float*  CST0  = (float*)(ws+alloc(32UL*1024*4));
  float*  CST1  = (float*)(ws+alloc(32UL*1024*4));
  float*  BIAS0 = (float*)(ws+alloc(4096UL*4));
  float*  BIAS1 = (float*)(ws+alloc(4096UL*4));
  ushort* TH0   = (ushort*)(ws+alloc(4096UL*512*2));
  ushort* TH1   = (ushort*)(ws+alloc(4096UL*256*2));
  float*  PARTH = (float*)(ws+alloc(4096UL*16*2*4));
  float*  PART0 = (float*)(ws+alloc(4096UL*16*2*4));
  float*  PART1 = (float*)(ws+alloc(4096UL*16*2*4));
  (void)ws_size; (void)in_sizes; (void)n_in; (void)out_size;

  // initial cell state
  hipMemcpyAsync(CST0, c0,        32*1024*4, hipMemcpyDeviceToDevice, stream);
  hipMemcpyAsync(CST1, c0+32768,  32*1024*4, hipMemcpyDeviceToDevice, stream);

  auto cvt=[&](const float* in, ushort* o, long n, long npad){
    int grid = (int)((npad/4 + 255)/256);
    cvt_k<<<grid,256,0,stream>>>(in,o,n,npad);
  };
  cvt(wih0, WIH0B, 4096L*1024, 4096L*1024);
  cvt(whh0, WHH0B, 4096L*1024, 4096L*1024);
  cvt(wih1, WIH1B, 4096L*1024, 4096L*1024);
  cvt(whh1, WHH1B, 4096L*1024, 4096L*1024);
  cvt(headW,HEADWB,20002L*1024, 20096L*1024);
  cvt(t0w1, T0W1B, 512L*1024,  512L*1024);
  cvt(t0w2, T0W2B, 30000L*512, 30080L*512);
  cvt(t1w1, T1W1B, 256L*1024,  256L*1024);
  cvt(t1w2, T1W2B, 50000L*256, 50048L*256);
  cvt(h0,        HB0, 32L*1024, 32L*1024);    // layer0 h init -> HB0 slot 0
  cvt(h0+32768,  HB1, 32L*1024, 32L*1024);    // layer1 h init -> HB1 slot 0
  bias_k<<<16,256,0,stream>>>(bih0,bhh0,BIAS0);
  bias_k<<<16,256,0,stream>>>(bih1,bhh1,BIAS1);

  emb_gather<<<4096,128,0,stream>>>(embW, tokens, XEMB);

  // layer 0: pregate + 128 recurrent steps
  gemm_bt<1><<<dim3(32,32),256,0,stream>>>(XEMB, WIH0B, PG, nullptr, BIAS0, 1024, 4096);
  for(int t=0;t<128;t++){
    lstm_step<<<64,256,0,stream>>>(HB0 + (size_t)t*32768, WHH0B,
                                   PG + (size_t)t*32*4096, CST0,
                                   HB0 + (size_t)(t+1)*32768);
  }
  // layer 1
  gemm_bt<1><<<dim3(32,32),256,0,stream>>>(HB0+32768, WIH1B, PG, nullptr, BIAS1, 1024, 4096);
  for(int t=0;t<128;t++){
    lstm_step<<<64,256,0,stream>>>(HB1 + (size_t)t*32768, WHH1B,
                                   PG + (size_t)t*32*4096, CST1,
                                   HB1 + (size_t)(t+1)*32768);
  }
  const ushort* FLAT = HB1 + 32768;   // [4096,1024] bf16

  // tail hidden projections
  gemm_bt<2><<<dim3(32,4),256,0,stream>>>(FLAT, T0W1B, nullptr, TH0, nullptr, 1024, 512);
  gemm_bt<2><<<dim3(32,2),256,0,stream>>>(FLAT, T1W1B, nullptr, TH1, nullptr, 1024, 256);

  // fused logit + online-LSE partials
  lse_gemm<<<dim3(32,16),256,0,stream>>>(FLAT, HEADWB, 1024, 20002, 157, 16, PARTH);
  lse_gemm<<<dim3(32,16),256,0,stream>>>(TH0,  T0W2B,  512,  30000, 235, 16, PART0);
  lse_gemm<<<dim3(32,16),256,0,stream>>>(TH1,  T1W2B,  256,  50000, 391, 16, PART1);

  combine_k<<<1024,256,0,stream>>>(targets, FLAT, HEADWB, TH0, T0W2B, TH1, T1W2B,
                                   PARTH, PART0, PART1, out);
  loss_k<<<1,256,0,stream>>>(out, out+4096);
}